// Round 5
// baseline (749.783 us; speedup 1.0000x reference)
//
#include <hip/hip_runtime.h>
#include <math.h>

#define IN_C  256
#define HID_C 128
#define OUT_C 64

// ---------------- edge dtype detection ----------------
// Reference creates int64 edge_index; harness docs say int32. Detect on
// device: if the first 64 values interpreted as int64 are all valid node
// ids, the buffer is int64 (int32 data would need every 2nd id == 0).
__global__ void detect_kernel(const void* edges, int E, int n_nodes, int* flag) {
    if (threadIdx.x == 0 && blockIdx.x == 0) {
        const long long* p = (const long long*)edges;
        int k = E < 64 ? E : 64;
        int is64 = 1;
        for (int i = 0; i < k; ++i) {
            long long v = p[i];
            if (v < 0 || v >= n_nodes) { is64 = 0; break; }
        }
        *flag = is64;
    }
}

__device__ __forceinline__ int load_edge(const void* edges, size_t idx, int is64) {
    return is64 ? (int)((const long long*)edges)[idx] : ((const int*)edges)[idx];
}

// non-temporal variant: don't pollute L2 (protects dirty ssrc lines in fill)
__device__ __forceinline__ int load_edge_nt(const void* edges, size_t idx, int is64) {
    return is64 ? (int)__builtin_nontemporal_load((const long long*)edges + idx)
                : __builtin_nontemporal_load((const int*)edges + idx);
}

// ---------------- degree count ----------------
__global__ void zero_counts(int* counts, int n, int* work_ctr) {
    int i = blockIdx.x * blockDim.x + threadIdx.x;
    if (i < n) counts[i] = 0;
    if (blockIdx.x == 0 && threadIdx.x < 8) work_ctr[threadIdx.x] = 0;
}

__global__ void count_deg(const void* edges, const int* __restrict__ flag, int* counts, int E) {
    const int f = *flag;
    int t = blockIdx.x * blockDim.x + threadIdx.x;
    int stride = gridDim.x * blockDim.x;
    for (int e = t; e < E; e += stride)
        atomicAdd(&counts[load_edge(edges, (size_t)E + e, f)], 1);
}

// ---------------- scan (block phase) + dis = rsqrt(deg+1) fused ----------------
__global__ void scan_block_dis(const int* __restrict__ counts, int* __restrict__ excl,
                               int* __restrict__ blockSums, float* __restrict__ dis, int n) {
    __shared__ int tmp[256];
    int i = blockIdx.x * 256 + threadIdx.x;
    int v = (i < n) ? counts[i] : 0;
    if (i < n) dis[i] = rsqrtf((float)v + 1.0f);   // +1 self-loop
    tmp[threadIdx.x] = v;
    __syncthreads();
    for (int off = 1; off < 256; off <<= 1) {
        int t = (threadIdx.x >= off) ? tmp[threadIdx.x - off] : 0;
        __syncthreads();
        if (threadIdx.x >= off) tmp[threadIdx.x] += t;
        __syncthreads();
    }
    if (i < n) excl[i] = tmp[threadIdx.x] - v;
    if (threadIdx.x == 255) blockSums[blockIdx.x] = tmp[255];
}

__global__ void scan_sums(int* blockSums, int nb) {  // nb <= 512, single block of 512
    __shared__ int tmp[512];
    int v = (threadIdx.x < nb) ? blockSums[threadIdx.x] : 0;
    tmp[threadIdx.x] = v;
    __syncthreads();
    for (int off = 1; off < 512; off <<= 1) {
        int t = (threadIdx.x >= off) ? tmp[threadIdx.x - off] : 0;
        __syncthreads();
        if (threadIdx.x >= off) tmp[threadIdx.x] += t;
        __syncthreads();
    }
    if (threadIdx.x < nb) blockSums[threadIdx.x] = tmp[threadIdx.x] - v;  // exclusive
}

__global__ void add_offsets_cursor(int* __restrict__ excl, const int* __restrict__ blockSums,
                                   int* __restrict__ cursor, int n) {
    int i = blockIdx.x * 256 + threadIdx.x;
    if (i < n) {
        int v = excl[i] + blockSums[blockIdx.x];
        excl[i] = v;
        cursor[i] = v;
    }
}

// ---------------- XCD-affine CSR fill ----------------
// Problem this solves (r3/r4 counters): random 4B ssrc stores from all 8 XCDs
// -> every 64B line partially dirty in 8 private L2s -> one 64B HBM writeback
// PER STORE (WRITE_SIZE was 106MB for 6.4MB of payload).
// Scheme: dst space split into 8 contiguous ranges; range r's ssrc positions
// are contiguous (~800KB, fits one XCD's 4MB L2). Work item = (chunk, range).
// Each block reads its XCC_ID and claims items of its own range first (per-
// range atomic counters), then falls through to other ranges -> every item
// claimed exactly once REGARDLESS of XCC read correctness; affinity is only
// a perf hint. Edge scans use non-temporal loads so streaming reads don't
// evict dirty ssrc lines; re-scans are served by memory-side L3.
#define FILL_CHUNK 1024   // edges per work item (256 thr x 4)
__global__ __launch_bounds__(256) void fill_csr_xcd(
    const void* edges, const int* __restrict__ flag,
    int* cursor, int* __restrict__ ssrc, int* work_ctr, int E, int n) {
    const int f = *flag;
    const int nchunks = (E + FILL_CHUNK - 1) / FILL_CHUNK;
    // hwreg(id=20 HW_REG_XCC_ID, offset=0, size=4): imm = ((4-1)<<11)|(0<<6)|20
    unsigned xcc = (unsigned)__builtin_amdgcn_s_getreg((3 << 11) | 20) & 7u;
    __shared__ int s_item;
    for (int rr = 0; rr < 8; ++rr) {
        const int r  = (xcc + rr) & 7;
        const int lo = (int)((long long)n * r / 8);
        const int hi = (int)((long long)n * (r + 1) / 8);
        while (true) {
            if (threadIdx.x == 0) s_item = atomicAdd(&work_ctr[r], 1);
            __syncthreads();
            const int item = s_item;
            __syncthreads();
            if (item >= nchunks) break;
            const size_t base = (size_t)item * FILL_CHUNK + threadIdx.x;
            #pragma unroll
            for (int k = 0; k < 4; ++k) {
                size_t e = base + (size_t)k * 256;
                if (e < (size_t)E) {
                    int d = load_edge_nt(edges, (size_t)E + e, f);
                    if (d >= lo && d < hi) {
                        int s = load_edge_nt(edges, e, f);
                        int pos = atomicAdd(&cursor[d], 1);
                        ssrc[pos] = s;
                    }
                }
            }
        }
    }
}

// ---------------- f32 GEMM, 128x128 tile, 8x8 micro, epilogue *dis[row] ----------------
template<int TM, int TN, int K, int KC>
__global__ __launch_bounds__(256) void gemm_scaled_88(
    const float* __restrict__ A, const float* __restrict__ B,
    const float* __restrict__ dis, float* __restrict__ C, int M) {
    __shared__ float As[KC][TM + 4];
    __shared__ float Bs[KC][TN + 4];
    const int tid = threadIdx.x;
    constexpr int TCN = TN / 8;            // 16
    const int tc = tid % TCN;
    const int tr = tid / TCN;              // 0..15
    const long long row0 = (long long)blockIdx.x * TM;
    float acc[8][8] = {};

    for (int k0 = 0; k0 < K; k0 += KC) {
        constexpr int A_LOADS = TM * KC / 4;
        #pragma unroll
        for (int i = tid; i < A_LOADS; i += 256) {
            int r  = i / (KC / 4);
            int kq = i % (KC / 4);
            long long row = row0 + r;
            float4 a = make_float4(0.f, 0.f, 0.f, 0.f);
            if (row < M) a = *(const float4*)(A + row * K + k0 + kq * 4);
            As[kq * 4 + 0][r] = a.x;
            As[kq * 4 + 1][r] = a.y;
            As[kq * 4 + 2][r] = a.z;
            As[kq * 4 + 3][r] = a.w;
        }
        constexpr int B_LOADS = KC * TN / 4;
        #pragma unroll
        for (int i = tid; i < B_LOADS; i += 256) {
            int kk = i / (TN / 4);
            int cq = i % (TN / 4);
            *(float4*)(&Bs[kk][cq * 4]) = *(const float4*)(B + (long long)(k0 + kk) * TN + cq * 4);
        }
        __syncthreads();
        #pragma unroll 8
        for (int kk = 0; kk < KC; ++kk) {
            float4 a0 = *(const float4*)(&As[kk][tr * 4]);
            float4 a1 = *(const float4*)(&As[kk][tr * 4 + TM / 2]);
            float4 b0 = *(const float4*)(&Bs[kk][tc * 4]);
            float4 b1 = *(const float4*)(&Bs[kk][tc * 4 + TN / 2]);
            float ar[8] = {a0.x, a0.y, a0.z, a0.w, a1.x, a1.y, a1.z, a1.w};
            float br[8] = {b0.x, b0.y, b0.z, b0.w, b1.x, b1.y, b1.z, b1.w};
            #pragma unroll
            for (int i = 0; i < 8; ++i)
                #pragma unroll
                for (int j = 0; j < 8; ++j)
                    acc[i][j] = fmaf(ar[i], br[j], acc[i][j]);
        }
        __syncthreads();
    }
    #pragma unroll
    for (int i = 0; i < 8; ++i) {
        long long r = row0 + (i < 4 ? tr * 4 + i : TM / 2 + tr * 4 + (i - 4));
        if (r >= M) continue;
        float d = dis[r];
        float4 v0 = make_float4(acc[i][0] * d, acc[i][1] * d, acc[i][2] * d, acc[i][3] * d);
        float4 v1 = make_float4(acc[i][4] * d, acc[i][5] * d, acc[i][6] * d, acc[i][7] * d);
        *(float4*)(C + r * TN + tc * 4) = v0;
        *(float4*)(C + r * TN + TN / 2 + tc * 4) = v1;
    }
}

// ---------------- f32 GEMM, 128x64 tile, 4x8 micro, epilogue *dis[row] ----------------
template<int TM, int TN, int K, int KC>
__global__ __launch_bounds__(256) void gemm_scaled_48(
    const float* __restrict__ A, const float* __restrict__ B,
    const float* __restrict__ dis, float* __restrict__ C, int M) {
    __shared__ float As[KC][TM + 4];
    __shared__ float Bs[KC][TN + 4];
    const int tid = threadIdx.x;
    constexpr int TCN = TN / 8;            // 8
    const int tc = tid % TCN;
    const int tr = tid / TCN;              // 0..31
    const long long row0 = (long long)blockIdx.x * TM;
    float acc[4][8] = {};

    for (int k0 = 0; k0 < K; k0 += KC) {
        constexpr int A_LOADS = TM * KC / 4;
        #pragma unroll
        for (int i = tid; i < A_LOADS; i += 256) {
            int r  = i / (KC / 4);
            int kq = i % (KC / 4);
            long long row = row0 + r;
            float4 a = make_float4(0.f, 0.f, 0.f, 0.f);
            if (row < M) a = *(const float4*)(A + row * K + k0 + kq * 4);
            As[kq * 4 + 0][r] = a.x;
            As[kq * 4 + 1][r] = a.y;
            As[kq * 4 + 2][r] = a.z;
            As[kq * 4 + 3][r] = a.w;
        }
        constexpr int B_LOADS = KC * TN / 4;
        #pragma unroll
        for (int i = tid; i < B_LOADS; i += 256) {
            int kk = i / (TN / 4);
            int cq = i % (TN / 4);
            *(float4*)(&Bs[kk][cq * 4]) = *(const float4*)(B + (long long)(k0 + kk) * TN + cq * 4);
        }
        __syncthreads();
        #pragma unroll 8
        for (int kk = 0; kk < KC; ++kk) {
            float4 a0 = *(const float4*)(&As[kk][tr * 4]);
            float4 b0 = *(const float4*)(&Bs[kk][tc * 4]);
            float4 b1 = *(const float4*)(&Bs[kk][tc * 4 + TN / 2]);
            float ar[4] = {a0.x, a0.y, a0.z, a0.w};
            float br[8] = {b0.x, b0.y, b0.z, b0.w, b1.x, b1.y, b1.z, b1.w};
            #pragma unroll
            for (int i = 0; i < 4; ++i)
                #pragma unroll
                for (int j = 0; j < 8; ++j)
                    acc[i][j] = fmaf(ar[i], br[j], acc[i][j]);
        }
        __syncthreads();
    }
    #pragma unroll
    for (int i = 0; i < 4; ++i) {
        long long r = row0 + tr * 4 + i;
        if (r >= M) continue;
        float d = dis[r];
        float4 v0 = make_float4(acc[i][0] * d, acc[i][1] * d, acc[i][2] * d, acc[i][3] * d);
        float4 v1 = make_float4(acc[i][4] * d, acc[i][5] * d, acc[i][6] * d, acc[i][7] * d);
        *(float4*)(C + r * TN + tc * 4) = v0;
        *(float4*)(C + r * TN + TN / 2 + tc * 4) = v1;
    }
}

// ---------------- CSR gather on pre-scaled hs = h*dis ----------------
// out[i] = b + dis[i]*(hs[i] + sum_j hs[src_j]); inner loop is pure gather+add.
template<int C, int NPB>
__global__ __launch_bounds__(256) void gather_layer(
    const float* __restrict__ hs, const int* __restrict__ row_ptr,
    const int* __restrict__ counts, const int* __restrict__ ssrc,
    const float* __restrict__ dis, const float* __restrict__ bias,
    float* __restrict__ outp, int n) {
    constexpr int TPN = C / 4;
    const int local = threadIdx.x / TPN;
    const int lane  = threadIdx.x % TPN;
    const int i = blockIdx.x * NPB + local;
    if (i >= n) return;
    const float4* h4 = (const float4*)hs;
    float di = dis[i];
    float4 acc = h4[(size_t)i * TPN + lane];   // self term (hs[i])
    const int start = row_ptr[i];
    const int cnt   = counts[i];
    const int* sp = ssrc + start;
    int j = 0;
    for (; j + 4 <= cnt; j += 4) {
        int s0 = sp[j], s1 = sp[j + 1], s2 = sp[j + 2], s3 = sp[j + 3];
        float4 v0 = h4[(size_t)s0 * TPN + lane];
        float4 v1 = h4[(size_t)s1 * TPN + lane];
        float4 v2 = h4[(size_t)s2 * TPN + lane];
        float4 v3 = h4[(size_t)s3 * TPN + lane];
        acc.x += (v0.x + v1.x) + (v2.x + v3.x);
        acc.y += (v0.y + v1.y) + (v2.y + v3.y);
        acc.z += (v0.z + v1.z) + (v2.z + v3.z);
        acc.w += (v0.w + v1.w) + (v2.w + v3.w);
    }
    for (; j < cnt; ++j) {
        int s = sp[j];
        float4 v = h4[(size_t)s * TPN + lane];
        acc.x += v.x; acc.y += v.y; acc.z += v.z; acc.w += v.w;
    }
    float4 bv = ((const float4*)bias)[lane];
    float4 o;
    o.x = bv.x + di * acc.x; o.y = bv.y + di * acc.y;
    o.z = bv.z + di * acc.z; o.w = bv.w + di * acc.w;
    ((float4*)outp)[(size_t)i * TPN + lane] = o;
}

extern "C" void kernel_launch(void* const* d_in, const int* in_sizes, int n_in,
                              void* d_out, int out_size, void* d_ws, size_t ws_size,
                              hipStream_t stream) {
    const float* x     = (const float*)d_in[0];
    const void*  edges = d_in[1];
    const float* W1    = (const float*)d_in[2];
    const float* b1    = (const float*)d_in[3];
    const float* W2    = (const float*)d_in[4];
    const float* b2    = (const float*)d_in[5];
    float* out = (float*)d_out;

    const int n = in_sizes[0] / IN_C;      // 100000
    const int E = in_sizes[1] / 2;         // 1600000
    const int nb = (n + 255) / 256;        // scan blocks (391)

    // ---- workspace carve-up (256B-aligned), ~110.7 MB ----
    char* ws = (char*)d_ws;
    size_t off = 0;
    auto alloc = [&](size_t bytes) { char* p = ws + off; off += (bytes + 255) & ~(size_t)255; return p; };
    int*   flag      = (int*)  alloc(4);
    int*   work_ctr  = (int*)  alloc(8 * 4);
    int*   counts    = (int*)  alloc((size_t)n * 4);
    int*   row_ptr   = (int*)  alloc((size_t)n * 4);
    int*   cursor    = (int*)  alloc((size_t)n * 4);
    int*   blockSums = (int*)  alloc(512 * 4);
    float* dis       = (float*)alloc((size_t)n * 4);
    int*   ssrc      = (int*)  alloc((size_t)E * 4);
    float* hs        = (float*)alloc((size_t)n * HID_C * 4);   // scaled h; reused as hs2
    float* agg       = (float*)alloc((size_t)n * HID_C * 4);

    // 1. edge dtype detect
    detect_kernel<<<1, 64, 0, stream>>>(edges, E, n, flag);

    // 2. degree (int) -> scan(+dis) -> cursor
    zero_counts<<<nb, 256, 0, stream>>>(counts, n, work_ctr);
    count_deg<<<(E / 4 + 255) / 256, 256, 0, stream>>>(edges, flag, counts, E);
    scan_block_dis<<<nb, 256, 0, stream>>>(counts, row_ptr, blockSums, dis, n);
    scan_sums<<<1, 512, 0, stream>>>(blockSums, nb);
    add_offsets_cursor<<<nb, 256, 0, stream>>>(row_ptr, blockSums, cursor, n);

    // 3. CSR fill, XCD-affine (writeback-merge in per-XCD L2)
    fill_csr_xcd<<<2048, 256, 0, stream>>>(edges, flag, cursor, ssrc, work_ctr, E, n);

    // 4. layer 1: hs = (x @ W1) * dis; agg = b1 + dis*(self + gather)
    gemm_scaled_88<128, HID_C, IN_C, 32><<<(n + 127) / 128, 256, 0, stream>>>(x, W1, dis, hs, n);
    gather_layer<HID_C, 8><<<(n + 7) / 8, 256, 0, stream>>>(hs, row_ptr, counts, ssrc, dis, b1, agg, n);

    // 5. layer 2: hs2 = (agg @ W2) * dis; out = b2 + dis*(self + gather)
    gemm_scaled_48<128, OUT_C, HID_C, 32><<<(n + 127) / 128, 256, 0, stream>>>(agg, W2, dis, hs, n);
    gather_layer<OUT_C, 16><<<(n + 15) / 16, 256, 0, stream>>>(hs, row_ptr, counts, ssrc, dis, b2, out, n);
}

// Round 6
// 418.724 us; speedup vs baseline: 1.7906x; 1.7906x over previous
//
#include <hip/hip_runtime.h>
#include <math.h>

#define IN_C  256
#define HID_C 128
#define OUT_C 64

// ---------------- edge dtype detection ----------------
// Reference creates int64 edge_index; harness docs say int32. Detect on
// device: if the first 64 values interpreted as int64 are all valid node
// ids, the buffer is int64 (int32 data would need every 2nd id == 0).
__global__ void detect_kernel(const void* edges, int E, int n_nodes, int* flag) {
    if (threadIdx.x == 0 && blockIdx.x == 0) {
        const long long* p = (const long long*)edges;
        int k = E < 64 ? E : 64;
        int is64 = 1;
        for (int i = 0; i < k; ++i) {
            long long v = p[i];
            if (v < 0 || v >= n_nodes) { is64 = 0; break; }
        }
        *flag = is64;
    }
}

__device__ __forceinline__ int load_edge(const void* edges, size_t idx, int is64) {
    return is64 ? (int)((const long long*)edges)[idx] : ((const int*)edges)[idx];
}

// ---------------- degree count + per-edge rank ----------------
// rank[e] = position of edge e within its dst segment (atomic return value).
// This moves the atomic-return dependency into the (already mandatory)
// counting pass; the CSR fill then needs NO atomics at all.
__global__ void zero_counts(int* counts, int n) {
    int i = blockIdx.x * blockDim.x + threadIdx.x;
    if (i < n) counts[i] = 0;
}

__global__ void count_deg_rank(const void* edges, const int* __restrict__ flag,
                               int* counts, int* __restrict__ rank, int E) {
    const int f = *flag;
    int t = blockIdx.x * blockDim.x + threadIdx.x;
    int stride = gridDim.x * blockDim.x;
    for (int e = t; e < E; e += stride) {
        int d = load_edge(edges, (size_t)E + e, f);
        rank[e] = atomicAdd(&counts[d], 1);   // rank store is coalesced
    }
}

// ---------------- scan (block phase) + dis = rsqrt(deg+1) fused ----------------
__global__ void scan_block_dis(const int* __restrict__ counts, int* __restrict__ excl,
                               int* __restrict__ blockSums, float* __restrict__ dis, int n) {
    __shared__ int tmp[256];
    int i = blockIdx.x * 256 + threadIdx.x;
    int v = (i < n) ? counts[i] : 0;
    if (i < n) dis[i] = rsqrtf((float)v + 1.0f);   // +1 self-loop
    tmp[threadIdx.x] = v;
    __syncthreads();
    for (int off = 1; off < 256; off <<= 1) {
        int t = (threadIdx.x >= off) ? tmp[threadIdx.x - off] : 0;
        __syncthreads();
        if (threadIdx.x >= off) tmp[threadIdx.x] += t;
        __syncthreads();
    }
    if (i < n) excl[i] = tmp[threadIdx.x] - v;
    if (threadIdx.x == 255) blockSums[blockIdx.x] = tmp[255];
}

__global__ void scan_sums(int* blockSums, int nb) {  // nb <= 512, single block of 512
    __shared__ int tmp[512];
    int v = (threadIdx.x < nb) ? blockSums[threadIdx.x] : 0;
    tmp[threadIdx.x] = v;
    __syncthreads();
    for (int off = 1; off < 512; off <<= 1) {
        int t = (threadIdx.x >= off) ? tmp[threadIdx.x - off] : 0;
        __syncthreads();
        if (threadIdx.x >= off) tmp[threadIdx.x] += t;
        __syncthreads();
    }
    if (threadIdx.x < nb) blockSums[threadIdx.x] = tmp[threadIdx.x] - v;  // exclusive
}

__global__ void add_offsets(int* __restrict__ excl, const int* __restrict__ blockSums, int n) {
    int i = blockIdx.x * 256 + threadIdx.x;
    if (i < n) excl[i] += blockSums[blockIdx.x];
}

// ---------------- CSR fill, atomic-free ----------------
// pos = row_ptr[d] + rank[e]. Streams: edges (coalesced), rank (coalesced),
// row_ptr (400KB read-only -> replicated in every XCD L2), ssrc store
// (scattered, fire-and-forget — no dependency chain).
__global__ __launch_bounds__(256) void fill_csr_rank(
    const void* edges, const int* __restrict__ flag,
    const int* __restrict__ row_ptr, const int* __restrict__ rank,
    int* __restrict__ ssrc, int E) {
    const int f = *flag;
    int t = blockIdx.x * blockDim.x + threadIdx.x;
    int stride = gridDim.x * blockDim.x;
    for (int e = t; e < E; e += stride) {
        int d = load_edge(edges, (size_t)E + e, f);
        int s = load_edge(edges, e, f);
        ssrc[row_ptr[d] + rank[e]] = s;
    }
}

// ---------------- f32 GEMM, 128x128 tile, 8x8 micro, epilogue *dis[row] ----------------
template<int TM, int TN, int K, int KC>
__global__ __launch_bounds__(256) void gemm_scaled_88(
    const float* __restrict__ A, const float* __restrict__ B,
    const float* __restrict__ dis, float* __restrict__ C, int M) {
    __shared__ float As[KC][TM + 4];
    __shared__ float Bs[KC][TN + 4];
    const int tid = threadIdx.x;
    constexpr int TCN = TN / 8;            // 16
    const int tc = tid % TCN;
    const int tr = tid / TCN;              // 0..15
    const long long row0 = (long long)blockIdx.x * TM;
    float acc[8][8] = {};

    for (int k0 = 0; k0 < K; k0 += KC) {
        constexpr int A_LOADS = TM * KC / 4;
        #pragma unroll
        for (int i = tid; i < A_LOADS; i += 256) {
            int r  = i / (KC / 4);
            int kq = i % (KC / 4);
            long long row = row0 + r;
            float4 a = make_float4(0.f, 0.f, 0.f, 0.f);
            if (row < M) a = *(const float4*)(A + row * K + k0 + kq * 4);
            As[kq * 4 + 0][r] = a.x;
            As[kq * 4 + 1][r] = a.y;
            As[kq * 4 + 2][r] = a.z;
            As[kq * 4 + 3][r] = a.w;
        }
        constexpr int B_LOADS = KC * TN / 4;
        #pragma unroll
        for (int i = tid; i < B_LOADS; i += 256) {
            int kk = i / (TN / 4);
            int cq = i % (TN / 4);
            *(float4*)(&Bs[kk][cq * 4]) = *(const float4*)(B + (long long)(k0 + kk) * TN + cq * 4);
        }
        __syncthreads();
        #pragma unroll 8
        for (int kk = 0; kk < KC; ++kk) {
            float4 a0 = *(const float4*)(&As[kk][tr * 4]);
            float4 a1 = *(const float4*)(&As[kk][tr * 4 + TM / 2]);
            float4 b0 = *(const float4*)(&Bs[kk][tc * 4]);
            float4 b1 = *(const float4*)(&Bs[kk][tc * 4 + TN / 2]);
            float ar[8] = {a0.x, a0.y, a0.z, a0.w, a1.x, a1.y, a1.z, a1.w};
            float br[8] = {b0.x, b0.y, b0.z, b0.w, b1.x, b1.y, b1.z, b1.w};
            #pragma unroll
            for (int i = 0; i < 8; ++i)
                #pragma unroll
                for (int j = 0; j < 8; ++j)
                    acc[i][j] = fmaf(ar[i], br[j], acc[i][j]);
        }
        __syncthreads();
    }
    #pragma unroll
    for (int i = 0; i < 8; ++i) {
        long long r = row0 + (i < 4 ? tr * 4 + i : TM / 2 + tr * 4 + (i - 4));
        if (r >= M) continue;
        float d = dis[r];
        float4 v0 = make_float4(acc[i][0] * d, acc[i][1] * d, acc[i][2] * d, acc[i][3] * d);
        float4 v1 = make_float4(acc[i][4] * d, acc[i][5] * d, acc[i][6] * d, acc[i][7] * d);
        *(float4*)(C + r * TN + tc * 4) = v0;
        *(float4*)(C + r * TN + TN / 2 + tc * 4) = v1;
    }
}

// ---------------- f32 GEMM, 128x64 tile, 4x8 micro, epilogue *dis[row] ----------------
template<int TM, int TN, int K, int KC>
__global__ __launch_bounds__(256) void gemm_scaled_48(
    const float* __restrict__ A, const float* __restrict__ B,
    const float* __restrict__ dis, float* __restrict__ C, int M) {
    __shared__ float As[KC][TM + 4];
    __shared__ float Bs[KC][TN + 4];
    const int tid = threadIdx.x;
    constexpr int TCN = TN / 8;            // 8
    const int tc = tid % TCN;
    const int tr = tid / TCN;              // 0..31
    const long long row0 = (long long)blockIdx.x * TM;
    float acc[4][8] = {};

    for (int k0 = 0; k0 < K; k0 += KC) {
        constexpr int A_LOADS = TM * KC / 4;
        #pragma unroll
        for (int i = tid; i < A_LOADS; i += 256) {
            int r  = i / (KC / 4);
            int kq = i % (KC / 4);
            long long row = row0 + r;
            float4 a = make_float4(0.f, 0.f, 0.f, 0.f);
            if (row < M) a = *(const float4*)(A + row * K + k0 + kq * 4);
            As[kq * 4 + 0][r] = a.x;
            As[kq * 4 + 1][r] = a.y;
            As[kq * 4 + 2][r] = a.z;
            As[kq * 4 + 3][r] = a.w;
        }
        constexpr int B_LOADS = KC * TN / 4;
        #pragma unroll
        for (int i = tid; i < B_LOADS; i += 256) {
            int kk = i / (TN / 4);
            int cq = i % (TN / 4);
            *(float4*)(&Bs[kk][cq * 4]) = *(const float4*)(B + (long long)(k0 + kk) * TN + cq * 4);
        }
        __syncthreads();
        #pragma unroll 8
        for (int kk = 0; kk < KC; ++kk) {
            float4 a0 = *(const float4*)(&As[kk][tr * 4]);
            float4 b0 = *(const float4*)(&Bs[kk][tc * 4]);
            float4 b1 = *(const float4*)(&Bs[kk][tc * 4 + TN / 2]);
            float ar[4] = {a0.x, a0.y, a0.z, a0.w};
            float br[8] = {b0.x, b0.y, b0.z, b0.w, b1.x, b1.y, b1.z, b1.w};
            #pragma unroll
            for (int i = 0; i < 4; ++i)
                #pragma unroll
                for (int j = 0; j < 8; ++j)
                    acc[i][j] = fmaf(ar[i], br[j], acc[i][j]);
        }
        __syncthreads();
    }
    #pragma unroll
    for (int i = 0; i < 4; ++i) {
        long long r = row0 + tr * 4 + i;
        if (r >= M) continue;
        float d = dis[r];
        float4 v0 = make_float4(acc[i][0] * d, acc[i][1] * d, acc[i][2] * d, acc[i][3] * d);
        float4 v1 = make_float4(acc[i][4] * d, acc[i][5] * d, acc[i][6] * d, acc[i][7] * d);
        *(float4*)(C + r * TN + tc * 4) = v0;
        *(float4*)(C + r * TN + TN / 2 + tc * 4) = v1;
    }
}

// ---------------- CSR gather on pre-scaled hs = h*dis ----------------
// out[i] = b + dis[i]*(hs[i] + sum_j hs[src_j]); inner loop is pure gather+add.
template<int C, int NPB>
__global__ __launch_bounds__(256) void gather_layer(
    const float* __restrict__ hs, const int* __restrict__ row_ptr,
    const int* __restrict__ counts, const int* __restrict__ ssrc,
    const float* __restrict__ dis, const float* __restrict__ bias,
    float* __restrict__ outp, int n) {
    constexpr int TPN = C / 4;
    const int local = threadIdx.x / TPN;
    const int lane  = threadIdx.x % TPN;
    const int i = blockIdx.x * NPB + local;
    if (i >= n) return;
    const float4* h4 = (const float4*)hs;
    float di = dis[i];
    float4 acc = h4[(size_t)i * TPN + lane];   // self term (hs[i])
    const int start = row_ptr[i];
    const int cnt   = counts[i];
    const int* sp = ssrc + start;
    int j = 0;
    for (; j + 4 <= cnt; j += 4) {
        int s0 = sp[j], s1 = sp[j + 1], s2 = sp[j + 2], s3 = sp[j + 3];
        float4 v0 = h4[(size_t)s0 * TPN + lane];
        float4 v1 = h4[(size_t)s1 * TPN + lane];
        float4 v2 = h4[(size_t)s2 * TPN + lane];
        float4 v3 = h4[(size_t)s3 * TPN + lane];
        acc.x += (v0.x + v1.x) + (v2.x + v3.x);
        acc.y += (v0.y + v1.y) + (v2.y + v3.y);
        acc.z += (v0.z + v1.z) + (v2.z + v3.z);
        acc.w += (v0.w + v1.w) + (v2.w + v3.w);
    }
    for (; j < cnt; ++j) {
        int s = sp[j];
        float4 v = h4[(size_t)s * TPN + lane];
        acc.x += v.x; acc.y += v.y; acc.z += v.z; acc.w += v.w;
    }
    float4 bv = ((const float4*)bias)[lane];
    float4 o;
    o.x = bv.x + di * acc.x; o.y = bv.y + di * acc.y;
    o.z = bv.z + di * acc.z; o.w = bv.w + di * acc.w;
    ((float4*)outp)[(size_t)i * TPN + lane] = o;
}

extern "C" void kernel_launch(void* const* d_in, const int* in_sizes, int n_in,
                              void* d_out, int out_size, void* d_ws, size_t ws_size,
                              hipStream_t stream) {
    const float* x     = (const float*)d_in[0];
    const void*  edges = d_in[1];
    const float* W1    = (const float*)d_in[2];
    const float* b1    = (const float*)d_in[3];
    const float* W2    = (const float*)d_in[4];
    const float* b2    = (const float*)d_in[5];
    float* out = (float*)d_out;

    const int n = in_sizes[0] / IN_C;      // 100000
    const int E = in_sizes[1] / 2;         // 1600000
    const int nb = (n + 255) / 256;        // scan blocks (391)

    // ---- workspace carve-up (256B-aligned), ~117 MB ----
    char* ws = (char*)d_ws;
    size_t off = 0;
    auto alloc = [&](size_t bytes) { char* p = ws + off; off += (bytes + 255) & ~(size_t)255; return p; };
    int*   flag      = (int*)  alloc(4);
    int*   counts    = (int*)  alloc((size_t)n * 4);
    int*   row_ptr   = (int*)  alloc((size_t)n * 4);
    int*   blockSums = (int*)  alloc(512 * 4);
    float* dis       = (float*)alloc((size_t)n * 4);
    int*   rank      = (int*)  alloc((size_t)E * 4);
    int*   ssrc      = (int*)  alloc((size_t)E * 4);
    float* hs        = (float*)alloc((size_t)n * HID_C * 4);   // scaled h; reused as hs2
    float* agg       = (float*)alloc((size_t)n * HID_C * 4);

    // 1. edge dtype detect
    detect_kernel<<<1, 64, 0, stream>>>(edges, E, n, flag);

    // 2. degree + per-edge rank (single atomic pass) -> scan(+dis)
    zero_counts<<<nb, 256, 0, stream>>>(counts, n);
    count_deg_rank<<<(E / 4 + 255) / 256, 256, 0, stream>>>(edges, flag, counts, rank, E);
    scan_block_dis<<<nb, 256, 0, stream>>>(counts, row_ptr, blockSums, dis, n);
    scan_sums<<<1, 512, 0, stream>>>(blockSums, nb);
    add_offsets<<<nb, 256, 0, stream>>>(row_ptr, blockSums, n);

    // 3. CSR fill: atomic-free, pos = row_ptr[d] + rank[e]
    fill_csr_rank<<<(E / 4 + 255) / 256, 256, 0, stream>>>(edges, flag, row_ptr, rank, ssrc, E);

    // 4. layer 1: hs = (x @ W1) * dis; agg = b1 + dis*(self + gather)
    gemm_scaled_88<128, HID_C, IN_C, 32><<<(n + 127) / 128, 256, 0, stream>>>(x, W1, dis, hs, n);
    gather_layer<HID_C, 8><<<(n + 7) / 8, 256, 0, stream>>>(hs, row_ptr, counts, ssrc, dis, b1, agg, n);

    // 5. layer 2: hs2 = (agg @ W2) * dis; out = b2 + dis*(self + gather)
    gemm_scaled_48<128, OUT_C, HID_C, 32><<<(n + 127) / 128, 256, 0, stream>>>(agg, W2, dis, hs, n);
    gather_layer<OUT_C, 16><<<(n + 15) / 16, 256, 0, stream>>>(hs, row_ptr, counts, ssrc, dis, b2, out, n);
}

// Round 7
// 332.911 us; speedup vs baseline: 2.2522x; 1.2578x over previous
//
#include <hip/hip_runtime.h>
#include <math.h>

#define IN_C  256
#define HID_C 128
#define OUT_C 64

// ---------------- bf16 helpers (bit ops; RNE pack) ----------------
__device__ __forceinline__ unsigned short f2bf(float f) {
    unsigned u = __float_as_uint(f);
    unsigned rounding = 0x7FFFu + ((u >> 16) & 1u);
    return (unsigned short)((u + rounding) >> 16);
}

// ---------------- edge dtype detection ----------------
// Reference creates int64 edge_index; harness docs say int32. Detect on
// device: if the first 64 values interpreted as int64 are all valid node
// ids, the buffer is int64 (int32 data would need every 2nd id == 0).
__global__ void detect_kernel(const void* edges, int E, int n_nodes, int* flag) {
    if (threadIdx.x == 0 && blockIdx.x == 0) {
        const long long* p = (const long long*)edges;
        int k = E < 64 ? E : 64;
        int is64 = 1;
        for (int i = 0; i < k; ++i) {
            long long v = p[i];
            if (v < 0 || v >= n_nodes) { is64 = 0; break; }
        }
        *flag = is64;
    }
}

__device__ __forceinline__ int load_edge(const void* edges, size_t idx, int is64) {
    return is64 ? (int)((const long long*)edges)[idx] : ((const int*)edges)[idx];
}

// ---------------- degree count + per-edge rank ----------------
__global__ void zero_counts(int* counts, int n) {
    int i = blockIdx.x * blockDim.x + threadIdx.x;
    if (i < n) counts[i] = 0;
}

__global__ void count_deg_rank(const void* edges, const int* __restrict__ flag,
                               int* counts, int* __restrict__ rank, int E) {
    const int f = *flag;
    int t = blockIdx.x * blockDim.x + threadIdx.x;
    int stride = gridDim.x * blockDim.x;
    for (int e = t; e < E; e += stride) {
        int d = load_edge(edges, (size_t)E + e, f);
        rank[e] = atomicAdd(&counts[d], 1);   // rank store is coalesced
    }
}

// ---------------- scan (block phase) + dis = rsqrt(deg+1) fused ----------------
__global__ void scan_block_dis(const int* __restrict__ counts, int* __restrict__ excl,
                               int* __restrict__ blockSums, float* __restrict__ dis, int n) {
    __shared__ int tmp[256];
    int i = blockIdx.x * 256 + threadIdx.x;
    int v = (i < n) ? counts[i] : 0;
    if (i < n) dis[i] = rsqrtf((float)v + 1.0f);   // +1 self-loop
    tmp[threadIdx.x] = v;
    __syncthreads();
    for (int off = 1; off < 256; off <<= 1) {
        int t = (threadIdx.x >= off) ? tmp[threadIdx.x - off] : 0;
        __syncthreads();
        if (threadIdx.x >= off) tmp[threadIdx.x] += t;
        __syncthreads();
    }
    if (i < n) excl[i] = tmp[threadIdx.x] - v;
    if (threadIdx.x == 255) blockSums[blockIdx.x] = tmp[255];
}

__global__ void scan_sums(int* blockSums, int nb) {  // nb <= 512, single block of 512
    __shared__ int tmp[512];
    int v = (threadIdx.x < nb) ? blockSums[threadIdx.x] : 0;
    tmp[threadIdx.x] = v;
    __syncthreads();
    for (int off = 1; off < 512; off <<= 1) {
        int t = (threadIdx.x >= off) ? tmp[threadIdx.x - off] : 0;
        __syncthreads();
        if (threadIdx.x >= off) tmp[threadIdx.x] += t;
        __syncthreads();
    }
    if (threadIdx.x < nb) blockSums[threadIdx.x] = tmp[threadIdx.x] - v;  // exclusive
}

__global__ void add_offsets(int* __restrict__ excl, const int* __restrict__ blockSums, int n) {
    int i = blockIdx.x * 256 + threadIdx.x;
    if (i < n) excl[i] += blockSums[blockIdx.x];
}

// ---------------- CSR fill, atomic-free ----------------
__global__ __launch_bounds__(256) void fill_csr_rank(
    const void* edges, const int* __restrict__ flag,
    const int* __restrict__ row_ptr, const int* __restrict__ rank,
    int* __restrict__ ssrc, int E) {
    const int f = *flag;
    int t = blockIdx.x * blockDim.x + threadIdx.x;
    int stride = gridDim.x * blockDim.x;
    for (int e = t; e < E; e += stride) {
        int d = load_edge(edges, (size_t)E + e, f);
        int s = load_edge(edges, e, f);
        ssrc[row_ptr[d] + rank[e]] = s;
    }
}

// ---------------- f32 GEMM, 128x128 tile, 8x8 micro, epilogue *dis[row] -> bf16 ----------------
template<int TM, int TN, int K, int KC>
__global__ __launch_bounds__(256) void gemm_scaled_88_bf(
    const float* __restrict__ A, const float* __restrict__ B,
    const float* __restrict__ dis, unsigned short* __restrict__ C, int M) {
    __shared__ float As[KC][TM + 4];
    __shared__ float Bs[KC][TN + 4];
    const int tid = threadIdx.x;
    constexpr int TCN = TN / 8;            // 16
    const int tc = tid % TCN;
    const int tr = tid / TCN;              // 0..15
    const long long row0 = (long long)blockIdx.x * TM;
    float acc[8][8] = {};

    for (int k0 = 0; k0 < K; k0 += KC) {
        constexpr int A_LOADS = TM * KC / 4;
        #pragma unroll
        for (int i = tid; i < A_LOADS; i += 256) {
            int r  = i / (KC / 4);
            int kq = i % (KC / 4);
            long long row = row0 + r;
            float4 a = make_float4(0.f, 0.f, 0.f, 0.f);
            if (row < M) a = *(const float4*)(A + row * K + k0 + kq * 4);
            As[kq * 4 + 0][r] = a.x;
            As[kq * 4 + 1][r] = a.y;
            As[kq * 4 + 2][r] = a.z;
            As[kq * 4 + 3][r] = a.w;
        }
        constexpr int B_LOADS = KC * TN / 4;
        #pragma unroll
        for (int i = tid; i < B_LOADS; i += 256) {
            int kk = i / (TN / 4);
            int cq = i % (TN / 4);
            *(float4*)(&Bs[kk][cq * 4]) = *(const float4*)(B + (long long)(k0 + kk) * TN + cq * 4);
        }
        __syncthreads();
        #pragma unroll 8
        for (int kk = 0; kk < KC; ++kk) {
            float4 a0 = *(const float4*)(&As[kk][tr * 4]);
            float4 a1 = *(const float4*)(&As[kk][tr * 4 + TM / 2]);
            float4 b0 = *(const float4*)(&Bs[kk][tc * 4]);
            float4 b1 = *(const float4*)(&Bs[kk][tc * 4 + TN / 2]);
            float ar[8] = {a0.x, a0.y, a0.z, a0.w, a1.x, a1.y, a1.z, a1.w};
            float br[8] = {b0.x, b0.y, b0.z, b0.w, b1.x, b1.y, b1.z, b1.w};
            #pragma unroll
            for (int i = 0; i < 8; ++i)
                #pragma unroll
                for (int j = 0; j < 8; ++j)
                    acc[i][j] = fmaf(ar[i], br[j], acc[i][j]);
        }
        __syncthreads();
    }
    #pragma unroll
    for (int i = 0; i < 8; ++i) {
        long long r = row0 + (i < 4 ? tr * 4 + i : TM / 2 + tr * 4 + (i - 4));
        if (r >= M) continue;
        float d = dis[r];
        ushort4 v0, v1;
        v0.x = f2bf(acc[i][0] * d); v0.y = f2bf(acc[i][1] * d);
        v0.z = f2bf(acc[i][2] * d); v0.w = f2bf(acc[i][3] * d);
        v1.x = f2bf(acc[i][4] * d); v1.y = f2bf(acc[i][5] * d);
        v1.z = f2bf(acc[i][6] * d); v1.w = f2bf(acc[i][7] * d);
        *(ushort4*)(C + r * TN + tc * 4) = v0;
        *(ushort4*)(C + r * TN + TN / 2 + tc * 4) = v1;
    }
}

// ---------------- f32 GEMM, 128x64 tile, 4x8 micro, epilogue *dis[row] -> bf16 ----------------
template<int TM, int TN, int K, int KC>
__global__ __launch_bounds__(256) void gemm_scaled_48_bf(
    const float* __restrict__ A, const float* __restrict__ B,
    const float* __restrict__ dis, unsigned short* __restrict__ C, int M) {
    __shared__ float As[KC][TM + 4];
    __shared__ float Bs[KC][TN + 4];
    const int tid = threadIdx.x;
    constexpr int TCN = TN / 8;            // 8
    const int tc = tid % TCN;
    const int tr = tid / TCN;              // 0..31
    const long long row0 = (long long)blockIdx.x * TM;
    float acc[4][8] = {};

    for (int k0 = 0; k0 < K; k0 += KC) {
        constexpr int A_LOADS = TM * KC / 4;
        #pragma unroll
        for (int i = tid; i < A_LOADS; i += 256) {
            int r  = i / (KC / 4);
            int kq = i % (KC / 4);
            long long row = row0 + r;
            float4 a = make_float4(0.f, 0.f, 0.f, 0.f);
            if (row < M) a = *(const float4*)(A + row * K + k0 + kq * 4);
            As[kq * 4 + 0][r] = a.x;
            As[kq * 4 + 1][r] = a.y;
            As[kq * 4 + 2][r] = a.z;
            As[kq * 4 + 3][r] = a.w;
        }
        constexpr int B_LOADS = KC * TN / 4;
        #pragma unroll
        for (int i = tid; i < B_LOADS; i += 256) {
            int kk = i / (TN / 4);
            int cq = i % (TN / 4);
            *(float4*)(&Bs[kk][cq * 4]) = *(const float4*)(B + (long long)(k0 + kk) * TN + cq * 4);
        }
        __syncthreads();
        #pragma unroll 8
        for (int kk = 0; kk < KC; ++kk) {
            float4 a0 = *(const float4*)(&As[kk][tr * 4]);
            float4 b0 = *(const float4*)(&Bs[kk][tc * 4]);
            float4 b1 = *(const float4*)(&Bs[kk][tc * 4 + TN / 2]);
            float ar[4] = {a0.x, a0.y, a0.z, a0.w};
            float br[8] = {b0.x, b0.y, b0.z, b0.w, b1.x, b1.y, b1.z, b1.w};
            #pragma unroll
            for (int i = 0; i < 4; ++i)
                #pragma unroll
                for (int j = 0; j < 8; ++j)
                    acc[i][j] = fmaf(ar[i], br[j], acc[i][j]);
        }
        __syncthreads();
    }
    #pragma unroll
    for (int i = 0; i < 4; ++i) {
        long long r = row0 + tr * 4 + i;
        if (r >= M) continue;
        float d = dis[r];
        ushort4 v0, v1;
        v0.x = f2bf(acc[i][0] * d); v0.y = f2bf(acc[i][1] * d);
        v0.z = f2bf(acc[i][2] * d); v0.w = f2bf(acc[i][3] * d);
        v1.x = f2bf(acc[i][4] * d); v1.y = f2bf(acc[i][5] * d);
        v1.z = f2bf(acc[i][6] * d); v1.w = f2bf(acc[i][7] * d);
        *(ushort4*)(C + r * TN + tc * 4) = v0;
        *(ushort4*)(C + r * TN + TN / 2 + tc * 4) = v1;
    }
}

// ---------------- CSR gather on bf16 hs (pre-scaled by dis[src]) ----------------
// out[i] = b + dis[i]*(hs[i] + sum_j hs[src_j]).  hs rows are bf16; each
// thread owns 8 channels = one uint4 (16B) per row; accumulate in f32.
// TPN = C/8 threads per node; NPB = 256/TPN nodes per block.
template<int C, int NPB>
__global__ __launch_bounds__(256) void gather_layer_bf(
    const unsigned short* __restrict__ hs, const int* __restrict__ row_ptr,
    const int* __restrict__ counts, const int* __restrict__ ssrc,
    const float* __restrict__ dis, const float* __restrict__ bias,
    float* __restrict__ outp, int n) {
    constexpr int TPN = C / 8;
    const int local = threadIdx.x / TPN;
    const int lane  = threadIdx.x % TPN;
    const int i = blockIdx.x * NPB + local;
    if (i >= n) return;
    const uint4* h4 = (const uint4*)hs;
    float di = dis[i];
    float acc[8] = {};
    auto accum = [&](uint4 u) {
        acc[0] += __uint_as_float(u.x << 16);
        acc[1] += __uint_as_float(u.x & 0xffff0000u);
        acc[2] += __uint_as_float(u.y << 16);
        acc[3] += __uint_as_float(u.y & 0xffff0000u);
        acc[4] += __uint_as_float(u.z << 16);
        acc[5] += __uint_as_float(u.z & 0xffff0000u);
        acc[6] += __uint_as_float(u.w << 16);
        acc[7] += __uint_as_float(u.w & 0xffff0000u);
    };
    accum(h4[(size_t)i * TPN + lane]);     // self term
    const int start = row_ptr[i];
    const int cnt   = counts[i];
    const int* sp = ssrc + start;
    int j = 0;
    for (; j + 4 <= cnt; j += 4) {
        int s0 = sp[j], s1 = sp[j + 1], s2 = sp[j + 2], s3 = sp[j + 3];
        uint4 v0 = h4[(size_t)s0 * TPN + lane];
        uint4 v1 = h4[(size_t)s1 * TPN + lane];
        uint4 v2 = h4[(size_t)s2 * TPN + lane];
        uint4 v3 = h4[(size_t)s3 * TPN + lane];
        accum(v0); accum(v1); accum(v2); accum(v3);
    }
    for (; j < cnt; ++j) {
        accum(h4[(size_t)sp[j] * TPN + lane]);
    }
    const float* bp = bias + lane * 8;
    float4 o0, o1;
    o0.x = bp[0] + di * acc[0]; o0.y = bp[1] + di * acc[1];
    o0.z = bp[2] + di * acc[2]; o0.w = bp[3] + di * acc[3];
    o1.x = bp[4] + di * acc[4]; o1.y = bp[5] + di * acc[5];
    o1.z = bp[6] + di * acc[6]; o1.w = bp[7] + di * acc[7];
    float* op = outp + (size_t)i * C + lane * 8;
    *(float4*)op = o0;
    *(float4*)(op + 4) = o1;
}

extern "C" void kernel_launch(void* const* d_in, const int* in_sizes, int n_in,
                              void* d_out, int out_size, void* d_ws, size_t ws_size,
                              hipStream_t stream) {
    const float* x     = (const float*)d_in[0];
    const void*  edges = d_in[1];
    const float* W1    = (const float*)d_in[2];
    const float* b1    = (const float*)d_in[3];
    const float* W2    = (const float*)d_in[4];
    const float* b2    = (const float*)d_in[5];
    float* out = (float*)d_out;

    const int n = in_sizes[0] / IN_C;      // 100000
    const int E = in_sizes[1] / 2;         // 1600000
    const int nb = (n + 255) / 256;        // scan blocks (391)

    // ---- workspace carve-up (256B-aligned), ~92 MB ----
    char* ws = (char*)d_ws;
    size_t off = 0;
    auto alloc = [&](size_t bytes) { char* p = ws + off; off += (bytes + 255) & ~(size_t)255; return p; };
    int*   flag      = (int*)  alloc(4);
    int*   counts    = (int*)  alloc((size_t)n * 4);
    int*   row_ptr   = (int*)  alloc((size_t)n * 4);
    int*   blockSums = (int*)  alloc(512 * 4);
    float* dis       = (float*)alloc((size_t)n * 4);
    int*   rank      = (int*)  alloc((size_t)E * 4);
    int*   ssrc      = (int*)  alloc((size_t)E * 4);
    unsigned short* hs = (unsigned short*)alloc((size_t)n * HID_C * 2);  // bf16; reused as hs2
    float* agg       = (float*)alloc((size_t)n * HID_C * 4);

    // 1. edge dtype detect
    detect_kernel<<<1, 64, 0, stream>>>(edges, E, n, flag);

    // 2. degree + per-edge rank (single atomic pass) -> scan(+dis)
    zero_counts<<<nb, 256, 0, stream>>>(counts, n);
    count_deg_rank<<<(E / 4 + 255) / 256, 256, 0, stream>>>(edges, flag, counts, rank, E);
    scan_block_dis<<<nb, 256, 0, stream>>>(counts, row_ptr, blockSums, dis, n);
    scan_sums<<<1, 512, 0, stream>>>(blockSums, nb);
    add_offsets<<<nb, 256, 0, stream>>>(row_ptr, blockSums, n);

    // 3. CSR fill: atomic-free, pos = row_ptr[d] + rank[e]
    fill_csr_rank<<<(E / 4 + 255) / 256, 256, 0, stream>>>(edges, flag, row_ptr, rank, ssrc, E);

    // 4. layer 1: hs = bf16((x @ W1) * dis); agg = b1 + dis*(self + gather)
    gemm_scaled_88_bf<128, HID_C, IN_C, 32><<<(n + 127) / 128, 256, 0, stream>>>(x, W1, dis, hs, n);
    gather_layer_bf<HID_C, 16><<<(n + 15) / 16, 256, 0, stream>>>(hs, row_ptr, counts, ssrc, dis, b1, agg, n);

    // 5. layer 2: hs2 = bf16((agg @ W2) * dis); out = b2 + dis*(self + gather)
    gemm_scaled_48_bf<128, OUT_C, HID_C, 32><<<(n + 127) / 128, 256, 0, stream>>>(agg, W2, dis, hs, n);
    gather_layer_bf<OUT_C, 32><<<(n + 31) / 32, 256, 0, stream>>>(hs, row_ptr, counts, ssrc, dis, b2, out, n);
}

// Round 8
// 264.231 us; speedup vs baseline: 2.8376x; 1.2599x over previous
//
#include <hip/hip_runtime.h>
#include <math.h>

#define IN_C  256
#define HID_C 128
#define OUT_C 64

typedef short bf16x8 __attribute__((ext_vector_type(8)));   // 8 bf16 = 4 VGPR
typedef float f32x4  __attribute__((ext_vector_type(4)));   // MFMA acc

// ---------------- bf16 helpers (bit ops; RNE pack) ----------------
__device__ __forceinline__ unsigned short f2bf(float f) {
    unsigned u = __float_as_uint(f);
    unsigned rounding = 0x7FFFu + ((u >> 16) & 1u);
    return (unsigned short)((u + rounding) >> 16);
}

// ---------------- edge dtype detection ----------------
// Reference creates int64 edge_index; harness docs say int32. Detect on
// device: if the first 64 values interpreted as int64 are all valid node
// ids, the buffer is int64 (int32 data would need every 2nd id == 0).
__global__ void detect_kernel(const void* edges, int E, int n_nodes, int* flag) {
    if (threadIdx.x == 0 && blockIdx.x == 0) {
        const long long* p = (const long long*)edges;
        int k = E < 64 ? E : 64;
        int is64 = 1;
        for (int i = 0; i < k; ++i) {
            long long v = p[i];
            if (v < 0 || v >= n_nodes) { is64 = 0; break; }
        }
        *flag = is64;
    }
}

__device__ __forceinline__ int load_edge(const void* edges, size_t idx, int is64) {
    return is64 ? (int)((const long long*)edges)[idx] : ((const int*)edges)[idx];
}

// ---------------- W -> Wt[col][k] bf16 (one-time, tiny) ----------------
__global__ void convert_wt(const float* __restrict__ W, unsigned short* __restrict__ Wt,
                           int K, int N) {
    int idx = blockIdx.x * 256 + threadIdx.x;   // over K*N, coalesced read
    if (idx >= K * N) return;
    int k = idx / N, n_ = idx % N;
    Wt[(size_t)n_ * K + k] = f2bf(W[idx]);
}

// ---------------- degree count + per-edge rank ----------------
__global__ void zero_counts(int* counts, int n) {
    int i = blockIdx.x * blockDim.x + threadIdx.x;
    if (i < n) counts[i] = 0;
}

__global__ void count_deg_rank(const void* edges, const int* __restrict__ flag,
                               int* counts, int* __restrict__ rank, int E) {
    const int f = *flag;
    int t = blockIdx.x * blockDim.x + threadIdx.x;
    int stride = gridDim.x * blockDim.x;
    for (int e = t; e < E; e += stride) {
        int d = load_edge(edges, (size_t)E + e, f);
        rank[e] = atomicAdd(&counts[d], 1);   // rank store is coalesced
    }
}

// ---------------- scan (block phase) + dis = rsqrt(deg+1) fused ----------------
__global__ void scan_block_dis(const int* __restrict__ counts, int* __restrict__ excl,
                               int* __restrict__ blockSums, float* __restrict__ dis, int n) {
    __shared__ int tmp[256];
    int i = blockIdx.x * 256 + threadIdx.x;
    int v = (i < n) ? counts[i] : 0;
    if (i < n) dis[i] = rsqrtf((float)v + 1.0f);   // +1 self-loop
    tmp[threadIdx.x] = v;
    __syncthreads();
    for (int off = 1; off < 256; off <<= 1) {
        int t = (threadIdx.x >= off) ? tmp[threadIdx.x - off] : 0;
        __syncthreads();
        if (threadIdx.x >= off) tmp[threadIdx.x] += t;
        __syncthreads();
    }
    if (i < n) excl[i] = tmp[threadIdx.x] - v;
    if (threadIdx.x == 255) blockSums[blockIdx.x] = tmp[255];
}

__global__ void scan_sums(int* blockSums, int nb) {  // nb <= 512, single block of 512
    __shared__ int tmp[512];
    int v = (threadIdx.x < nb) ? blockSums[threadIdx.x] : 0;
    tmp[threadIdx.x] = v;
    __syncthreads();
    for (int off = 1; off < 512; off <<= 1) {
        int t = (threadIdx.x >= off) ? tmp[threadIdx.x - off] : 0;
        __syncthreads();
        if (threadIdx.x >= off) tmp[threadIdx.x] += t;
        __syncthreads();
    }
    if (threadIdx.x < nb) blockSums[threadIdx.x] = tmp[threadIdx.x] - v;  // exclusive
}

__global__ void add_offsets(int* __restrict__ excl, const int* __restrict__ blockSums, int n) {
    int i = blockIdx.x * 256 + threadIdx.x;
    if (i < n) excl[i] += blockSums[blockIdx.x];
}

// ---------------- CSR fill, atomic-free ----------------
__global__ __launch_bounds__(256) void fill_csr_rank(
    const void* edges, const int* __restrict__ flag,
    const int* __restrict__ row_ptr, const int* __restrict__ rank,
    int* __restrict__ ssrc, int E) {
    const int f = *flag;
    int t = blockIdx.x * blockDim.x + threadIdx.x;
    int stride = gridDim.x * blockDim.x;
    for (int e = t; e < E; e += stride) {
        int d = load_edge(edges, (size_t)E + e, f);
        int s = load_edge(edges, e, f);
        ssrc[row_ptr[d] + rank[e]] = s;
    }
}

// ---------------- MFMA bf16 GEMM: C_bf16[i][c] = bf16( (A@W)[i][c] * dis[i] ) ----------------
// A: f32 [M][K] (converted to bf16 during staging); Wt: bf16 [TN][K] (pre-transposed).
// TM=128, KC=64, 256 threads (4 waves); wave w owns rows [w*32, w*32+32).
// mfma_f32_16x16x32_bf16 layouts (m89-verified family):
//   A frag: row = lane&15, k = ksub*32 + 8*(lane>>4) + j
//   B frag: col = lane&15, same k     -> B staged column-major (Wt) for b128 reads
//   C/D:    col = lane&15, row = 4*(lane>>4) + reg
// LDS rows padded to 72 bf16 (144B = 36 dwords): row-to-row bank shift +4,
// 16 rows -> 2-way conflict max (free, m136); 144 = 16*9 keeps b128 aligned.
template<int TN, int K>
__global__ __launch_bounds__(256) void gemm_mfma_bf(
    const float* __restrict__ A, const unsigned short* __restrict__ Wt,
    const float* __restrict__ dis, unsigned short* __restrict__ C, int M) {
    constexpr int TM = 128, KC = 64, NCF = TN / 16;
    __shared__ unsigned short A_lds[TM][72];
    __shared__ unsigned short B_lds[TN][72];
    const int tid  = threadIdx.x;
    const int wave = tid >> 6;
    const int lane = tid & 63;
    const int q    = lane >> 4;      // quad-group 0..3
    const int cl   = lane & 15;
    const long long row0 = (long long)blockIdx.x * TM;

    f32x4 acc[2][NCF];
    const f32x4 fzero = {0.f, 0.f, 0.f, 0.f};
    #pragma unroll
    for (int rf = 0; rf < 2; ++rf)
        #pragma unroll
        for (int cf = 0; cf < NCF; ++cf) acc[rf][cf] = fzero;

    for (int k0 = 0; k0 < K; k0 += KC) {
        // stage A chunk with f32->bf16 conversion: 128 rows x 64 k
        #pragma unroll
        for (int p = 0; p < TM * KC / 4 / 256; ++p) {
            int i = p * 256 + tid;
            int r = i >> 4, kq = i & 15;
            long long row = row0 + r;
            float4 a = make_float4(0.f, 0.f, 0.f, 0.f);
            if (row < M) a = *(const float4*)(A + row * K + k0 + kq * 4);
            union { unsigned short u[4]; uint2 v; } t;
            t.u[0] = f2bf(a.x); t.u[1] = f2bf(a.y);
            t.u[2] = f2bf(a.z); t.u[3] = f2bf(a.w);
            *(uint2*)&A_lds[r][kq * 4] = t.v;
        }
        // stage B chunk (already bf16, column-major): TN cols x 64 k, 16B copies
        #pragma unroll
        for (int p = 0; p < TN * KC / 8 / 256; ++p) {
            int i = p * 256 + tid;
            int c = i >> 3, kq = i & 7;
            *(uint4*)&B_lds[c][kq * 8] =
                *(const uint4*)(Wt + (size_t)c * K + k0 + kq * 8);
        }
        __syncthreads();
        #pragma unroll
        for (int ksub = 0; ksub < KC / 32; ++ksub) {
            const int kk = ksub * 32 + 8 * q;
            bf16x8 af[2];
            #pragma unroll
            for (int rf = 0; rf < 2; ++rf)
                af[rf] = *(const bf16x8*)&A_lds[wave * 32 + rf * 16 + cl][kk];
            #pragma unroll
            for (int cf = 0; cf < NCF; ++cf) {
                bf16x8 bfr = *(const bf16x8*)&B_lds[cf * 16 + cl][kk];
                acc[0][cf] = __builtin_amdgcn_mfma_f32_16x16x32_bf16(af[0], bfr, acc[0][cf], 0, 0, 0);
                acc[1][cf] = __builtin_amdgcn_mfma_f32_16x16x32_bf16(af[1], bfr, acc[1][cf], 0, 0, 0);
            }
        }
        __syncthreads();
    }
    // epilogue: *dis[row], pack bf16, store
    #pragma unroll
    for (int rf = 0; rf < 2; ++rf) {
        #pragma unroll
        for (int j = 0; j < 4; ++j) {
            long long row = row0 + wave * 32 + rf * 16 + q * 4 + j;
            if (row >= M) continue;
            float d = dis[row];
            #pragma unroll
            for (int cf = 0; cf < NCF; ++cf)
                C[row * TN + cf * 16 + cl] = f2bf(acc[rf][cf][j] * d);
        }
    }
}

// ---------------- CSR gather on bf16 hs (pre-scaled by dis[src]) ----------------
// out[i] = b + dis[i]*(hs[i] + sum_j hs[src_j]).  hs rows are bf16; each
// thread owns 8 channels = one uint4 (16B) per row; accumulate in f32.
template<int C, int NPB>
__global__ __launch_bounds__(256) void gather_layer_bf(
    const unsigned short* __restrict__ hs, const int* __restrict__ row_ptr,
    const int* __restrict__ counts, const int* __restrict__ ssrc,
    const float* __restrict__ dis, const float* __restrict__ bias,
    float* __restrict__ outp, int n) {
    constexpr int TPN = C / 8;
    const int local = threadIdx.x / TPN;
    const int lane  = threadIdx.x % TPN;
    const int i = blockIdx.x * NPB + local;
    if (i >= n) return;
    const uint4* h4 = (const uint4*)hs;
    float di = dis[i];
    float acc[8] = {};
    auto accum = [&](uint4 u) {
        acc[0] += __uint_as_float(u.x << 16);
        acc[1] += __uint_as_float(u.x & 0xffff0000u);
        acc[2] += __uint_as_float(u.y << 16);
        acc[3] += __uint_as_float(u.y & 0xffff0000u);
        acc[4] += __uint_as_float(u.z << 16);
        acc[5] += __uint_as_float(u.z & 0xffff0000u);
        acc[6] += __uint_as_float(u.w << 16);
        acc[7] += __uint_as_float(u.w & 0xffff0000u);
    };
    accum(h4[(size_t)i * TPN + lane]);     // self term
    const int start = row_ptr[i];
    const int cnt   = counts[i];
    const int* sp = ssrc + start;
    int j = 0;
    for (; j + 4 <= cnt; j += 4) {
        int s0 = sp[j], s1 = sp[j + 1], s2 = sp[j + 2], s3 = sp[j + 3];
        uint4 v0 = h4[(size_t)s0 * TPN + lane];
        uint4 v1 = h4[(size_t)s1 * TPN + lane];
        uint4 v2 = h4[(size_t)s2 * TPN + lane];
        uint4 v3 = h4[(size_t)s3 * TPN + lane];
        accum(v0); accum(v1); accum(v2); accum(v3);
    }
    for (; j < cnt; ++j) {
        accum(h4[(size_t)sp[j] * TPN + lane]);
    }
    const float* bp = bias + lane * 8;
    float4 o0, o1;
    o0.x = bp[0] + di * acc[0]; o0.y = bp[1] + di * acc[1];
    o0.z = bp[2] + di * acc[2]; o0.w = bp[3] + di * acc[3];
    o1.x = bp[4] + di * acc[4]; o1.y = bp[5] + di * acc[5];
    o1.z = bp[6] + di * acc[6]; o1.w = bp[7] + di * acc[7];
    float* op = outp + (size_t)i * C + lane * 8;
    *(float4*)op = o0;
    *(float4*)(op + 4) = o1;
}

extern "C" void kernel_launch(void* const* d_in, const int* in_sizes, int n_in,
                              void* d_out, int out_size, void* d_ws, size_t ws_size,
                              hipStream_t stream) {
    const float* x     = (const float*)d_in[0];
    const void*  edges = d_in[1];
    const float* W1    = (const float*)d_in[2];
    const float* b1    = (const float*)d_in[3];
    const float* W2    = (const float*)d_in[4];
    const float* b2    = (const float*)d_in[5];
    float* out = (float*)d_out;

    const int n = in_sizes[0] / IN_C;      // 100000
    const int E = in_sizes[1] / 2;         // 1600000
    const int nb = (n + 255) / 256;        // scan blocks (391)

    // ---- workspace carve-up (256B-aligned), ~92 MB ----
    char* ws = (char*)d_ws;
    size_t off = 0;
    auto alloc = [&](size_t bytes) { char* p = ws + off; off += (bytes + 255) & ~(size_t)255; return p; };
    int*   flag      = (int*)  alloc(4);
    int*   counts    = (int*)  alloc((size_t)n * 4);
    int*   row_ptr   = (int*)  alloc((size_t)n * 4);
    int*   blockSums = (int*)  alloc(512 * 4);
    float* dis       = (float*)alloc((size_t)n * 4);
    int*   rank      = (int*)  alloc((size_t)E * 4);
    int*   ssrc      = (int*)  alloc((size_t)E * 4);
    unsigned short* hs  = (unsigned short*)alloc((size_t)n * HID_C * 2);  // bf16; reused as hs2
    float* agg       = (float*)alloc((size_t)n * HID_C * 4);
    unsigned short* Wt1 = (unsigned short*)alloc((size_t)IN_C * HID_C * 2);
    unsigned short* Wt2 = (unsigned short*)alloc((size_t)HID_C * OUT_C * 2);

    // 1. edge dtype detect + one-time weight transpose/convert
    detect_kernel<<<1, 64, 0, stream>>>(edges, E, n, flag);
    convert_wt<<<(IN_C * HID_C + 255) / 256, 256, 0, stream>>>(W1, Wt1, IN_C, HID_C);
    convert_wt<<<(HID_C * OUT_C + 255) / 256, 256, 0, stream>>>(W2, Wt2, HID_C, OUT_C);

    // 2. degree + per-edge rank (single atomic pass) -> scan(+dis)
    zero_counts<<<nb, 256, 0, stream>>>(counts, n);
    count_deg_rank<<<(E / 4 + 255) / 256, 256, 0, stream>>>(edges, flag, counts, rank, E);
    scan_block_dis<<<nb, 256, 0, stream>>>(counts, row_ptr, blockSums, dis, n);
    scan_sums<<<1, 512, 0, stream>>>(blockSums, nb);
    add_offsets<<<nb, 256, 0, stream>>>(row_ptr, blockSums, n);

    // 3. CSR fill: atomic-free, pos = row_ptr[d] + rank[e]
    fill_csr_rank<<<(E / 4 + 255) / 256, 256, 0, stream>>>(edges, flag, row_ptr, rank, ssrc, E);

    // 4. layer 1: hs = bf16((x @ W1) * dis) via MFMA; agg = b1 + dis*(self + gather)
    gemm_mfma_bf<HID_C, IN_C><<<(n + 127) / 128, 256, 0, stream>>>(x, Wt1, dis, hs, n);
    gather_layer_bf<HID_C, 16><<<(n + 15) / 16, 256, 0, stream>>>(hs, row_ptr, counts, ssrc, dis, b1, agg, n);

    // 5. layer 2: hs2 = bf16((agg @ W2) * dis) via MFMA; out = b2 + dis*(self + gather)
    gemm_mfma_bf<OUT_C, HID_C><<<(n + 127) / 128, 256, 0, stream>>>(agg, Wt2, dis, hs, n);
    gather_layer_bf<OUT_C, 32><<<(n + 31) / 32, 256, 0, stream>>>(hs, row_ptr, counts, ssrc, dis, b2, out, n);
}

// Round 9
// 248.051 us; speedup vs baseline: 3.0227x; 1.0652x over previous
//
#include <hip/hip_runtime.h>
#include <math.h>

#define IN_C  256
#define HID_C 128
#define OUT_C 64

typedef short bf16x8 __attribute__((ext_vector_type(8)));   // 8 bf16 = 4 VGPR
typedef float f32x4  __attribute__((ext_vector_type(4)));   // MFMA acc

// ---------------- bf16 helpers (bit ops; RNE pack) ----------------
__device__ __forceinline__ unsigned short f2bf(float f) {
    unsigned u = __float_as_uint(f);
    unsigned rounding = 0x7FFFu + ((u >> 16) & 1u);
    return (unsigned short)((u + rounding) >> 16);
}

// ---------------- edge dtype detection ----------------
__global__ void detect_kernel(const void* edges, int E, int n_nodes, int* flag) {
    if (threadIdx.x == 0 && blockIdx.x == 0) {
        const long long* p = (const long long*)edges;
        int k = E < 64 ? E : 64;
        int is64 = 1;
        for (int i = 0; i < k; ++i) {
            long long v = p[i];
            if (v < 0 || v >= n_nodes) { is64 = 0; break; }
        }
        *flag = is64;
    }
}

__device__ __forceinline__ int load_edge(const void* edges, size_t idx, int is64) {
    return is64 ? (int)((const long long*)edges)[idx] : ((const int*)edges)[idx];
}

// ---------------- W -> Wt[col][k] bf16 (one-time, tiny) ----------------
__global__ void convert_wt(const float* __restrict__ W, unsigned short* __restrict__ Wt,
                           int K, int N) {
    int idx = blockIdx.x * 256 + threadIdx.x;
    if (idx >= K * N) return;
    int k = idx / N, n_ = idx % N;
    Wt[(size_t)n_ * K + k] = f2bf(W[idx]);
}

__global__ void zero8(int* counts8, int n8) {
    int i = blockIdx.x * 256 + threadIdx.x;
    if (i < n8) counts8[i] = 0;
}

// ---------------- FUSED: x->bf16 convert || XCD-replica degree count + rank ----------------
// Convert branch: streaming BW. Count branch: atomic-latency. No LDS, both
// high-occupancy -> true overlap (r4's failure was the LDS-cap, absent here).
// counts8 layout [xcc][d]: a 64B line holds 16 dst of ONE replica -> only one
// XCD ever touches it -> line stays in that XCD's L2, contention/line /8.
// rank[e] = local_rank | (xcc<<28); correct for ANY xcc value (0..7).
__global__ __launch_bounds__(256) void conv_count(
    const float* __restrict__ x, unsigned short* __restrict__ xb, int nconv,
    const void* edges, const int* __restrict__ flag,
    int* counts8, int* __restrict__ rank, int E, int n, int CONV) {
    const int bid = blockIdx.x;
    if (bid < CONV) {
        int t = bid * 256 + threadIdx.x;
        int stride = CONV * 256;
        for (int i = t; i < nconv; i += stride) {
            const float4* p = (const float4*)(x + (size_t)i * 8);
            float4 a = p[0], b = p[1];
            union { unsigned short u[8]; uint4 v; } t8;
            t8.u[0] = f2bf(a.x); t8.u[1] = f2bf(a.y); t8.u[2] = f2bf(a.z); t8.u[3] = f2bf(a.w);
            t8.u[4] = f2bf(b.x); t8.u[5] = f2bf(b.y); t8.u[6] = f2bf(b.z); t8.u[7] = f2bf(b.w);
            *(uint4*)(xb + (size_t)i * 8) = t8.v;
        }
        return;
    }
    int e = (bid - CONV) * 256 + threadIdx.x;
    if (e >= E) return;
    const int f = *flag;
    int d = load_edge(edges, (size_t)E + e, f);
    // hwreg(id=20 HW_REG_XCC_ID, offset=0, size=4): imm = ((4-1)<<11)|20
    unsigned xcc = (unsigned)__builtin_amdgcn_s_getreg((3 << 11) | 20) & 7u;
    int rl = atomicAdd(&counts8[(size_t)xcc * n + d], 1);
    rank[e] = rl | (int)(xcc << 28);
}

// ---------------- scan over summed replicas + xoff + dis, block phase ----------------
__global__ void scan8_block_dis(const int* __restrict__ counts8, int* __restrict__ xoff,
                                int* __restrict__ deg, int* __restrict__ excl,
                                int* __restrict__ blockSums, float* __restrict__ dis, int n) {
    __shared__ int tmp[256];
    int i = blockIdx.x * 256 + threadIdx.x;
    int v = 0;
    if (i < n) {
        int s = 0;
        #pragma unroll
        for (int xg = 0; xg < 8; ++xg) {
            int c = counts8[(size_t)xg * n + i];
            xoff[(size_t)xg * n + i] = s;
            s += c;
        }
        v = s;
        deg[i] = s;
        dis[i] = rsqrtf((float)s + 1.0f);   // +1 self-loop
    }
    tmp[threadIdx.x] = v;
    __syncthreads();
    for (int off = 1; off < 256; off <<= 1) {
        int t = (threadIdx.x >= off) ? tmp[threadIdx.x - off] : 0;
        __syncthreads();
        if (threadIdx.x >= off) tmp[threadIdx.x] += t;
        __syncthreads();
    }
    if (i < n) excl[i] = tmp[threadIdx.x] - v;
    if (threadIdx.x == 255) blockSums[blockIdx.x] = tmp[255];
}

__global__ void scan_sums(int* blockSums, int nb) {  // nb <= 512
    __shared__ int tmp[512];
    int v = (threadIdx.x < nb) ? blockSums[threadIdx.x] : 0;
    tmp[threadIdx.x] = v;
    __syncthreads();
    for (int off = 1; off < 512; off <<= 1) {
        int t = (threadIdx.x >= off) ? tmp[threadIdx.x - off] : 0;
        __syncthreads();
        if (threadIdx.x >= off) tmp[threadIdx.x] += t;
        __syncthreads();
    }
    if (threadIdx.x < nb) blockSums[threadIdx.x] = tmp[threadIdx.x] - v;
}

__global__ void add_offsets(int* __restrict__ excl, const int* __restrict__ blockSums, int n) {
    int i = blockIdx.x * 256 + threadIdx.x;
    if (i < n) excl[i] += blockSums[blockIdx.x];
}

// ---------------- CSR fill, atomic-free (replica-rank version) ----------------
__global__ __launch_bounds__(256) void fill_csr_rank(
    const void* edges, const int* __restrict__ flag,
    const int* __restrict__ row_ptr, const int* __restrict__ xoff,
    const int* __restrict__ rank, int* __restrict__ ssrc, int E, int n) {
    const int f = *flag;
    int e = blockIdx.x * 256 + threadIdx.x;
    if (e >= E) return;
    int d = load_edge(edges, (size_t)E + e, f);
    int s = load_edge(edges, e, f);
    int rk = rank[e];
    int pos = row_ptr[d] + xoff[(size_t)(rk >> 28) * n + d] + (rk & 0x0FFFFFFF);
    ssrc[pos] = s;
}

// ---------------- MFMA bf16 GEMM (bf16 A in memory): C = bf16((A@Wt^T)*dis[row]) ----------------
// TM=64, KC=64, 256 thr (4 waves), wave owns a 16-row strip.
// LDS: linear rows (128B), T2 XOR-swizzle col16 ^= row&7 -> conflict-free
// ds_write AND ds_read (G4 / m201). Fragments (r8 HW-verified convention):
//   A: row=lane&15, k=ksub*32+8*(lane>>4)+j ; B: col=lane&15, same k
//   C/D: col=lane&15, row=4*(lane>>4)+reg
template<int TN, int K>
__global__ __launch_bounds__(256) void gemm_mfma_bb(
    const unsigned short* __restrict__ A, const unsigned short* __restrict__ Wt,
    const float* __restrict__ dis, unsigned short* __restrict__ C, int M) {
    constexpr int TM = 64, KC = 64, NCF = TN / 16;
    __shared__ __align__(16) unsigned short A_lds[TM * KC];
    __shared__ __align__(16) unsigned short B_lds[TN * KC];
    const int tid  = threadIdx.x;
    const int wave = tid >> 6;
    const int lane = tid & 63;
    const int q    = lane >> 4;
    const int cl   = lane & 15;
    const long long row0 = (long long)blockIdx.x * TM;

    f32x4 acc[NCF];
    const f32x4 fzero = {0.f, 0.f, 0.f, 0.f};
    #pragma unroll
    for (int cf = 0; cf < NCF; ++cf) acc[cf] = fzero;

    for (int k0 = 0; k0 < K; k0 += KC) {
        // stage A: 64 rows x 128B, xor-swizzled 16B units (tail rows read ws slack)
        #pragma unroll
        for (int p = 0; p < 2; ++p) {
            int i = p * 256 + tid;
            int r = i >> 3, c = i & 7;
            uint4 v = *(const uint4*)(A + (row0 + r) * K + k0 + c * 8);
            *(uint4*)((char*)A_lds + r * 128 + ((c ^ (r & 7)) * 16)) = v;
        }
        // stage B: TN rows x 128B
        #pragma unroll
        for (int p = 0; p < TN / 32; ++p) {
            int i = p * 256 + tid;
            int bc = i >> 3, c = i & 7;
            uint4 v = *(const uint4*)(Wt + (size_t)bc * K + k0 + c * 8);
            *(uint4*)((char*)B_lds + bc * 128 + ((c ^ (bc & 7)) * 16)) = v;
        }
        __syncthreads();
        #pragma unroll
        for (int ksub = 0; ksub < 2; ++ksub) {
            const int cidx = ksub * 4 + q;
            const int r = wave * 16 + cl;
            bf16x8 af = *(const bf16x8*)((const char*)A_lds + r * 128 + ((cidx ^ (r & 7)) * 16));
            #pragma unroll
            for (int cf = 0; cf < NCF; ++cf) {
                const int bc = cf * 16 + cl;
                bf16x8 bfr = *(const bf16x8*)((const char*)B_lds + bc * 128 + ((cidx ^ (bc & 7)) * 16));
                acc[cf] = __builtin_amdgcn_mfma_f32_16x16x32_bf16(af, bfr, acc[cf], 0, 0, 0);
            }
        }
        __syncthreads();
    }
    #pragma unroll
    for (int j = 0; j < 4; ++j) {
        long long row = row0 + wave * 16 + q * 4 + j;
        if (row >= M) continue;
        float d = dis[row];
        #pragma unroll
        for (int cf = 0; cf < NCF; ++cf)
            C[row * TN + cf * 16 + cl] = f2bf(acc[cf][j] * d);
    }
}

// ---------------- CSR gather on bf16 hs; output f32 or bf16 ----------------
template<int C, int NPB, bool OBF>
__global__ __launch_bounds__(256) void gather_layer_bf(
    const unsigned short* __restrict__ hs, const int* __restrict__ row_ptr,
    const int* __restrict__ deg, const int* __restrict__ ssrc,
    const float* __restrict__ dis, const float* __restrict__ bias,
    void* __restrict__ outp, int n) {
    constexpr int TPN = C / 8;
    const int local = threadIdx.x / TPN;
    const int lane  = threadIdx.x % TPN;
    const int i = blockIdx.x * NPB + local;
    if (i >= n) return;
    const uint4* h4 = (const uint4*)hs;
    float di = dis[i];
    float acc[8] = {};
    auto accum = [&](uint4 u) {
        acc[0] += __uint_as_float(u.x << 16);
        acc[1] += __uint_as_float(u.x & 0xffff0000u);
        acc[2] += __uint_as_float(u.y << 16);
        acc[3] += __uint_as_float(u.y & 0xffff0000u);
        acc[4] += __uint_as_float(u.z << 16);
        acc[5] += __uint_as_float(u.z & 0xffff0000u);
        acc[6] += __uint_as_float(u.w << 16);
        acc[7] += __uint_as_float(u.w & 0xffff0000u);
    };
    accum(h4[(size_t)i * TPN + lane]);     // self term
    const int start = row_ptr[i];
    const int cnt   = deg[i];
    const int* sp = ssrc + start;
    int j = 0;
    for (; j + 4 <= cnt; j += 4) {
        int s0 = sp[j], s1 = sp[j + 1], s2 = sp[j + 2], s3 = sp[j + 3];
        uint4 v0 = h4[(size_t)s0 * TPN + lane];
        uint4 v1 = h4[(size_t)s1 * TPN + lane];
        uint4 v2 = h4[(size_t)s2 * TPN + lane];
        uint4 v3 = h4[(size_t)s3 * TPN + lane];
        accum(v0); accum(v1); accum(v2); accum(v3);
    }
    for (; j < cnt; ++j) accum(h4[(size_t)sp[j] * TPN + lane]);
    const float* bp = bias + lane * 8;
    float o[8];
    #pragma unroll
    for (int k = 0; k < 8; ++k) o[k] = bp[k] + di * acc[k];
    if constexpr (OBF) {
        union { unsigned short u[8]; uint4 v; } t8;
        #pragma unroll
        for (int k = 0; k < 8; ++k) t8.u[k] = f2bf(o[k]);
        *(uint4*)((unsigned short*)outp + (size_t)i * C + lane * 8) = t8.v;
    } else {
        float* op = (float*)outp + (size_t)i * C + lane * 8;
        *(float4*)op = make_float4(o[0], o[1], o[2], o[3]);
        *(float4*)(op + 4) = make_float4(o[4], o[5], o[6], o[7]);
    }
}

extern "C" void kernel_launch(void* const* d_in, const int* in_sizes, int n_in,
                              void* d_out, int out_size, void* d_ws, size_t ws_size,
                              hipStream_t stream) {
    const float* x     = (const float*)d_in[0];
    const void*  edges = d_in[1];
    const float* W1    = (const float*)d_in[2];
    const float* b1    = (const float*)d_in[3];
    const float* W2    = (const float*)d_in[4];
    const float* b2    = (const float*)d_in[5];
    float* out = (float*)d_out;

    const int n = in_sizes[0] / IN_C;      // 100000
    const int E = in_sizes[1] / 2;         // 1600000
    const int nb = (n + 255) / 256;        // 391

    // ---- workspace carve-up (256B-aligned), ~123 MB ----
    char* ws = (char*)d_ws;
    size_t off = 0;
    auto alloc = [&](size_t bytes) { char* p = ws + off; off += (bytes + 255) & ~(size_t)255; return p; };
    int*   flag      = (int*)  alloc(4);
    int*   counts8   = (int*)  alloc((size_t)n * 8 * 4);
    int*   xoff      = (int*)  alloc((size_t)n * 8 * 4);
    int*   deg       = (int*)  alloc((size_t)n * 4);
    int*   row_ptr   = (int*)  alloc((size_t)n * 4);
    int*   blockSums = (int*)  alloc(512 * 4);
    float* dis       = (float*)alloc((size_t)n * 4);
    int*   rank      = (int*)  alloc((size_t)E * 4);
    int*   ssrc      = (int*)  alloc((size_t)E * 4);
    unsigned short* xb   = (unsigned short*)alloc((size_t)(n + 64) * IN_C * 2);   // bf16 x (+tail pad)
    unsigned short* hs   = (unsigned short*)alloc((size_t)(n + 64) * HID_C * 2);  // layer1 hs; reused as hs2
    unsigned short* aggb = (unsigned short*)alloc((size_t)(n + 64) * HID_C * 2);  // bf16 layer-1 output

    // 1. detect + weight transpose/convert + zero replica counters
    detect_kernel<<<1, 64, 0, stream>>>(edges, E, n, flag);
    convert_wt<<<(IN_C * HID_C + 255) / 256, 256, 0, stream>>>(W1, (unsigned short*)hs, IN_C, HID_C); // temp? no:
    // NOTE: Wt1/Wt2 need dedicated storage (hs is overwritten later... keep separate):
    // (allocated below to keep diff minimal)
    unsigned short* Wt1 = (unsigned short*)alloc((size_t)IN_C * HID_C * 2);
    unsigned short* Wt2 = (unsigned short*)alloc((size_t)HID_C * OUT_C * 2);
    convert_wt<<<(IN_C * HID_C + 255) / 256, 256, 0, stream>>>(W1, Wt1, IN_C, HID_C);
    convert_wt<<<(HID_C * OUT_C + 255) / 256, 256, 0, stream>>>(W2, Wt2, HID_C, OUT_C);
    zero8<<<(n * 8 + 255) / 256, 256, 0, stream>>>(counts8, n * 8);

    // 2. FUSED: x->bf16 || replica count+rank
    const int CONV = 512;
    const int nconv = n * IN_C / 8;
    conv_count<<<CONV + (E + 255) / 256, 256, 0, stream>>>(
        x, xb, nconv, edges, flag, counts8, rank, E, n, CONV);

    // 3. scan (+xoff, +deg, +dis) -> row_ptr
    scan8_block_dis<<<nb, 256, 0, stream>>>(counts8, xoff, deg, row_ptr, blockSums, dis, n);
    scan_sums<<<1, 512, 0, stream>>>(blockSums, nb);
    add_offsets<<<nb, 256, 0, stream>>>(row_ptr, blockSums, n);

    // 4. CSR fill (atomic-free)
    fill_csr_rank<<<(E + 255) / 256, 256, 0, stream>>>(edges, flag, row_ptr, xoff, rank, ssrc, E, n);

    // 5. layer 1: hs = bf16((xb@W1)*dis); aggb = bf16(b1 + dis*(self+gather))
    gemm_mfma_bb<HID_C, IN_C><<<(n + 63) / 64, 256, 0, stream>>>(xb, Wt1, dis, hs, n);
    gather_layer_bf<HID_C, 16, true><<<(n + 15) / 16, 256, 0, stream>>>(hs, row_ptr, deg, ssrc, dis, b1, aggb, n);

    // 6. layer 2: hs2 = bf16((aggb@W2)*dis); out = b2 + dis*(self+gather)
    gemm_mfma_bb<OUT_C, HID_C><<<(n + 63) / 64, 256, 0, stream>>>(aggb, Wt2, dis, hs, n);
    gather_layer_bf<OUT_C, 32, false><<<(n + 31) / 32, 256, 0, stream>>>(hs, row_ptr, deg, ssrc, dis, b2, out, n);
}